// Round 10
// baseline (674.884 us; speedup 1.0000x reference)
//
#include <hip/hip_runtime.h>
#include <hip/hip_bf16.h>
#include <cstddef>
#include <cstdint>

#define T_TOK 1024
#define HDIM  2048
#define NEXP  64
#define IDIM  768
#define TOPK  8

using f32x4 = __attribute__((ext_vector_type(4))) float;
using s16x8 = __attribute__((ext_vector_type(8))) short;

// ---- workspace layout (bytes) ----
static constexpr size_t XBF_OFF = 0;                                   // bf16 X: 4 MiB
static constexpr size_t CNT_OFF = (size_t)T_TOK * HDIM * 2;            // 64 ints
static constexpr size_t OFF_OFF = CNT_OFF + 256;                       // 65 ints
static constexpr size_t QM_OFF  = CNT_OFF + 768;                       // nrg
static constexpr size_t RGL_OFF = CNT_OFF + 1024;                      // rowgroup list (<=768 ints)
static constexpr size_t TOK_OFF = CNT_OFF + 4096;                      // 64*1024 ints
static constexpr size_t WT_OFF  = TOK_OFF + (size_t)NEXP * T_TOK * 4;  // 64*1024 floats
static constexpr size_t HH_OFF  = WT_OFF  + (size_t)NEXP * T_TOK * 4;  // 8192*768 bf16

__device__ __forceinline__ short f2bf(float f) {
  union { __hip_bfloat16 b; short s; } u;
  u.b = __float2bfloat16(f);
  return u.s;
}
__device__ __forceinline__ uint32_t pk2(float lo, float hi) {
  return ((uint32_t)(uint16_t)f2bf(hi) << 16) | (uint16_t)f2bf(lo);
}
__device__ __forceinline__ void barrier_raw() {
  asm volatile("" ::: "memory");
  __builtin_amdgcn_s_barrier();
  asm volatile("" ::: "memory");
}
#define WAIT_LGKM0() asm volatile("s_waitcnt lgkmcnt(0)" ::: "memory")

// ---------------- router (+ fused fp32->bf16 convert of X) ----------------
__global__ __launch_bounds__(256) void router_kernel(
    const float* __restrict__ X, const float* __restrict__ GW,
    __hip_bfloat16* __restrict__ Xb,
    int* __restrict__ cnt, int* __restrict__ tokl, float* __restrict__ wtl) {
  __shared__ float xs[HDIM];
  __shared__ float lg[NEXP];
  const int t = blockIdx.x;
  const int tid = threadIdx.x;
  const f32x4* xr = (const f32x4*)(X + (size_t)t * HDIM);
#pragma unroll
  for (int i = 0; i < 2; ++i) {
    f32x4 v = xr[tid + i * 256];
    *(f32x4*)&xs[(tid + i * 256) * 4] = v;
  }
  __syncthreads();
  {
    union { short h[8]; int4 q; } u;
#pragma unroll
    for (int j = 0; j < 8; ++j) u.h[j] = f2bf(xs[tid * 8 + j]);
    *(int4*)((char*)Xb + ((size_t)t * HDIM + tid * 8) * 2) = u.q;
  }
  const int wid = tid >> 6, lane = tid & 63;
  for (int ee = 0; ee < 16; ++ee) {
    const int e = wid * 16 + ee;
    const float* g = GW + (size_t)e * HDIM;
    float acc = 0.f;
    for (int i = lane; i < HDIM; i += 64) acc += xs[i] * g[i];
#pragma unroll
    for (int s = 32; s; s >>= 1) acc += __shfl_xor(acc, s);
    if (lane == 0) lg[e] = acc;
  }
  __syncthreads();
  if (tid < 64) {
    const float v = lg[tid];
    float m = v;
#pragma unroll
    for (int s = 32; s; s >>= 1) m = fmaxf(m, __shfl_xor(m, s));
    const float p = expf(v - m);
    float den = p;
#pragma unroll
    for (int s = 32; s; s >>= 1) den += __shfl_xor(den, s);
    float work = p / den;
    float my_v = 0.f; int my_e = 0;
    float topsum = 0.f;
#pragma unroll
    for (int k = 0; k < TOPK; ++k) {
      float mv = work;
#pragma unroll
      for (int s = 32; s; s >>= 1) mv = fmaxf(mv, __shfl_xor(mv, s));
      unsigned long long ball = __ballot(work == mv);
      const int idx = __ffsll(ball) - 1;   // lowest index on ties (matches lax.top_k)
      topsum += mv;
      if (tid == k) { my_v = mv; my_e = idx; }
      if (tid == idx) work = -1.f;
    }
    if (tid < TOPK) {
      const float w = my_v / topsum;
      const int slot = atomicAdd(&cnt[my_e], 1);
      tokl[my_e * T_TOK + slot] = t;
      wtl[my_e * T_TOK + slot] = w;
    }
  }
}

// ---------------- prefix scan + rowgroup list (BM=96) ----------------
__global__ void scan_kernel(const int* __restrict__ cnt, int* __restrict__ offs,
                            int* __restrict__ rgl, int* __restrict__ qm) {
  if (threadIdx.x == 0) {
    int a = 0, nrg = 0;
    for (int e = 0; e < NEXP; ++e) {
      offs[e] = a;
      const int ne = cnt[e];
      a += ne;
      for (int t = 0; t * 96 < ne; ++t) rgl[nrg++] = (e << 4) | t;
    }
    offs[NEXP] = a;
    qm[2] = nrg;
  }
}

// ===================== gateup: BM=96, BN=128, 2-pass =====================
// item = (rowgroup of 96, nc of 6); grid 768 static (itot ~= 768, 1/block).
// B: whole-row 512B float2 instructions; E/O named-set reg staging -> pk2
// -> LDS double buffer; kp = consecutive-k pair rows of 512B.
#define GU_LOADA_(S)                                       \
    xa0_##S = *(const int4*)pap;                           \
    xa1_##S = *(const int4*)(pap + 8);                     \
    pap += 32;
#define GU_LOADB_(S)                                       \
    v0_##S = *(const float2*)(pbp);                        \
    v1_##S = *(const float2*)(pbp + IDIM);                 \
    v2_##S = *(const float2*)(pbp + 2 * IDIM);             \
    v3_##S = *(const float2*)(pbp + 3 * IDIM);             \
    v4_##S = *(const float2*)(pbp + 4 * IDIM);             \
    v5_##S = *(const float2*)(pbp + 5 * IDIM);             \
    v6_##S = *(const float2*)(pbp + 6 * IDIM);             \
    v7_##S = *(const float2*)(pbp + 7 * IDIM);             \
    pbp += (size_t)32 * IDIM;
#define GU_LOADSET(S) { if (doA) { GU_LOADA_(S) } GU_LOADB_(S) }

#define GU_WRITESET(S, BUF) {                              \
    char* base_ = sL + (BUF) * 14336;                      \
    if (doA) {                                             \
      *(int4*)(base_ + adst0) = xa0_##S;                   \
      *(int4*)(base_ + adst1) = xa1_##S;                   \
    }                                                      \
    uint2 w_;                                              \
    w_.x = pk2(v0_##S.x, v1_##S.x); w_.y = pk2(v0_##S.y, v1_##S.y); \
    *(uint2*)(base_ + bdst) = w_;                          \
    w_.x = pk2(v2_##S.x, v3_##S.x); w_.y = pk2(v2_##S.y, v3_##S.y); \
    *(uint2*)(base_ + bdst + 512) = w_;                    \
    w_.x = pk2(v4_##S.x, v5_##S.x); w_.y = pk2(v4_##S.y, v5_##S.y); \
    *(uint2*)(base_ + bdst + 1024) = w_;                   \
    w_.x = pk2(v6_##S.x, v7_##S.x); w_.y = pk2(v6_##S.y, v7_##S.y); \
    *(uint2*)(base_ + bdst + 1536) = w_; }

#define GU_STEP(LS, WS, RB, WB, DO_LOAD, DO_WRITE) {       \
    if (DO_LOAD) GU_LOADSET(LS)                            \
    const char* bb_ = sL + (RB) * 14336;                   \
    s16x8 af0 = *(const s16x8*)(bb_ + aoff0);              \
    s16x8 af1 = *(const s16x8*)(bb_ + aoff1);              \
    s16x8 af2 = *(const s16x8*)(bb_ + aoff2);              \
    s16x8 bf[4];                                           \
    _Pragma("unroll") for (int nf = 0; nf < 4; ++nf) {     \
      const char* p_ = bb_ + boffs[nf];                    \
      union { uint32_t u[4]; s16x8 v; } w_;                \
      w_.u[0] = *(const uint32_t*)p_;                      \
      w_.u[1] = *(const uint32_t*)(p_ + 512);              \
      w_.u[2] = *(const uint32_t*)(p_ + 1024);             \
      w_.u[3] = *(const uint32_t*)(p_ + 1536);             \
      bf[nf] = w_.v; }                                     \
    WAIT_LGKM0();                                          \
    barrier_raw();                                         \
    if (DO_WRITE) { GU_WRITESET(WS, WB) WAIT_LGKM0(); }    \
    barrier_raw();                                         \
    _Pragma("unroll") for (int nf = 0; nf < 4; ++nf) {     \
      acc[0][nf] = __builtin_amdgcn_mfma_f32_16x16x32_bf16(af0, bf[nf], acc[0][nf], 0, 0, 0); \
      acc[1][nf] = __builtin_amdgcn_mfma_f32_16x16x32_bf16(af1, bf[nf], acc[1][nf], 0, 0, 0); \
      acc[2][nf] = __builtin_amdgcn_mfma_f32_16x16x32_bf16(af2, bf[nf], acc[2][nf], 0, 0, 0); } }

__global__ __launch_bounds__(256, 3) void gateup_kernel(
    const __hip_bfloat16* __restrict__ Xb, const float* __restrict__ WG,
    const float* __restrict__ WU, const int* __restrict__ cnt,
    const int* __restrict__ offs, const int* __restrict__ tokl,
    const float* __restrict__ wtl, __hip_bfloat16* __restrict__ Hh,
    const int* __restrict__ qm, const int* __restrict__ rgl) {
  __shared__ __align__(16) char sL[2 * 14336];   // per buf: A 6144 + B 8192
  const int tid = threadIdx.x, lane = tid & 63, wid = tid >> 6;
  const int m = lane >> 4, c = lane & 15;
  const int wr = wid >> 1, wc = wid & 1;
  // A producer (tid < 192): row = tid>>1, half = tid&1 (k chunks half*2, half*2+1)
  const bool doA = (tid < 192);
  const int arow = tid >> 1, ahalf = tid & 1;
  const int asw = arow & 3;
  const int adst0 = arow * 64 + (((ahalf * 2 + 0) ^ asw) << 4);
  const int adst1 = arow * 64 + (((ahalf * 2 + 1) ^ asw) << 4);
  // B producer: wave wid stages k-rows wid*8 .. wid*8+7 -> kp wid*4 .. wid*4+3
  const int bdst = 6144 + (wid * 4) * 512 + (((lane * 2) ^ ((wid & 1) << 4))) * 4;
  // fragment offsets
  const int aswr = (m ^ (c & 3)) << 4;
  const int aoff0 = (wr * 48 + 0 * 16 + c) * 64 + aswr;
  const int aoff1 = (wr * 48 + 1 * 16 + c) * 64 + aswr;
  const int aoff2 = (wr * 48 + 2 * 16 + c) * 64 + aswr;
  int boffs[4];
#pragma unroll
  for (int nf = 0; nf < 4; ++nf) {
    const int col = wc * 64 + nf * 16 + c;
    boffs[nf] = 6144 + (m * 4) * 512 + (col ^ ((m & 1) << 4)) * 4;
  }
  const int itot = qm[2] * 6;

  for (int it = blockIdx.x; it < itot; it += 768) {
    const int rg = rgl[it / 6];
    const int e = rg >> 4, ti = rg & 15, nc = it % 6;
    const int ne = cnt[e];
    const int nrows = min(96, ne - ti * 96);
    const int nb = nc * 128;
    const int cbase = offs[e] + ti * 96;
    const int tbase = e * T_TOK + ti * 96;

    const short* paBase = (const short*)Xb
        + (size_t)tokl[tbase + min(arow, nrows - 1)] * HDIM + ahalf * 16;
    const float* pbG = WG + (size_t)e * HDIM * IDIM + (size_t)(wid * 8) * IDIM + nb + lane * 2;
    const float* pbU = WU + (size_t)e * HDIM * IDIM + (size_t)(wid * 8) * IDIM + nb + lane * 2;

    f32x4 acc[3][4];
    int4  xa0_E{}, xa1_E{}, xa0_O{}, xa1_O{};
    float2 v0_E{}, v1_E{}, v2_E{}, v3_E{}, v4_E{}, v5_E{}, v6_E{}, v7_E{};
    float2 v0_O{}, v1_O{}, v2_O{}, v3_O{}, v4_O{}, v5_O{}, v6_O{}, v7_O{};

    for (int pass = 0; pass < 2; ++pass) {
      const short* pap = paBase;
      const float* pbp = pass ? pbU : pbG;
#pragma unroll
      for (int i = 0; i < 3; ++i)
#pragma unroll
        for (int nf = 0; nf < 4; ++nf)
#pragma unroll
          for (int r = 0; r < 4; ++r) acc[i][nf][r] = 0.f;

      GU_LOADSET(E)            // tile 0
      GU_LOADSET(O)            // tile 1
      GU_WRITESET(E, 0)
      WAIT_LGKM0();
      barrier_raw();
      for (int p = 0; p < 31; ++p) {
        GU_STEP(E, O, 0, 1, true, true)
        GU_STEP(O, E, 1, 0, true, true)
      }
      GU_STEP(E, O, 0, 1, false, true)
      GU_STEP(O, E, 1, 0, false, false)

      if (pass == 0) {
        // park raw g in Hh
#pragma unroll
        for (int mi = 0; mi < 3; ++mi) {
          const int rb = wr * 48 + mi * 16 + m * 4;
#pragma unroll
          for (int nf = 0; nf < 4; ++nf) {
            const int colg = nb + wc * 64 + nf * 16 + c;
#pragma unroll
            for (int r = 0; r < 4; ++r) {
              const int row = rb + r;
              if (row < nrows)
                Hh[(size_t)(cbase + row) * IDIM + colg] = __float2bfloat16(acc[mi][nf][r]);
            }
          }
        }
        barrier_raw();
      } else {
        // h = silu(g) * u * wt
#pragma unroll
        for (int mi = 0; mi < 3; ++mi) {
          const int rb = wr * 48 + mi * 16 + m * 4;
          const int rbs = min(rb, (nrows - 1) & ~3);   // aligned, in-bounds
          const f32x4 wt4 = *(const f32x4*)&wtl[tbase + rbs];
#pragma unroll
          for (int nf = 0; nf < 4; ++nf) {
            const int colg = nb + wc * 64 + nf * 16 + c;
#pragma unroll
            for (int r = 0; r < 4; ++r) {
              const int row = rb + r;
              if (row < nrows) {
                __hip_bfloat16* hp = Hh + (size_t)(cbase + row) * IDIM + colg;
                const float g = __bfloat162float(*hp);
                const float uu = acc[mi][nf][r];
                const float h = (g / (1.f + __expf(-g))) * uu * wt4[r];
                *hp = __float2bfloat16(h);
              }
            }
          }
        }
      }
    }
  }
}

// ===================== down: BM=96, BN=512 =====================
// item = (rowgroup, hc of 4); grid 256 x 512 threads (itot ~= 512, 2/block).
// B: 1KB f32x4 half-row instructions; kp pairs = consecutive k-rows:
// (wid*4+0, wid*4+1) -> kp wid*2 ; (wid*4+2, wid*4+3) -> kp wid*2+1.
#define DN_LOADA_(S)                                       \
    xa0_##S = *(const int4*)pap;                           \
    xa1_##S = *(const int4*)(pap + 8);                     \
    pap += 32;
#define DN_LOADB_(S)                                       \
    v0_##S = *(const f32x4*)(pbp);                         \
    v1_##S = *(const f32x4*)(pbp + 256);                   \
    v2_##S = *(const f32x4*)(pbp + HDIM);                  \
    v3_##S = *(const f32x4*)(pbp + HDIM + 256);            \
    v4_##S = *(const f32x4*)(pbp + 2 * HDIM);              \
    v5_##S = *(const f32x4*)(pbp + 2 * HDIM + 256);        \
    v6_##S = *(const f32x4*)(pbp + 3 * HDIM);              \
    v7_##S = *(const f32x4*)(pbp + 3 * HDIM + 256);        \
    pbp += (size_t)32 * HDIM;
#define DN_LOADSET(S) { if (doA) { DN_LOADA_(S) } DN_LOADB_(S) }

#define DN_PK4(d_, pa_, pb_) {                             \
    d_.u[0] = pk2(pa_[0], pb_[0]);                         \
    d_.u[1] = pk2(pa_[1], pb_[1]);                         \
    d_.u[2] = pk2(pa_[2], pb_[2]);                         \
    d_.u[3] = pk2(pa_[3], pb_[3]); }

#define DN_WRITESET(S, BUF) {                              \
    char* base_ = sL + (BUF) * 38912;                      \
    if (doA) {                                             \
      *(int4*)(base_ + adst0) = xa0_##S;                   \
      *(int4*)(base_ + adst1) = xa1_##S;                   \
    }                                                      \
    union { uint32_t u[4]; int4 q; } w_;                   \
    DN_PK4(w_, v0_##S, v2_##S)                             \
    *(int4*)(base_ + bdst) = w_.q;          /* kp_a lo  */ \
    DN_PK4(w_, v1_##S, v3_##S)                             \
    *(int4*)(base_ + bdst + 1024) = w_.q;   /* kp_a hi  */ \
    DN_PK4(w_, v4_##S, v6_##S)                             \
    *(int4*)(base_ + bdst + 2048) = w_.q;   /* kp_b lo  */ \
    DN_PK4(w_, v5_##S, v7_##S)                             \
    *(int4*)(base_ + bdst + 3072) = w_.q;   /* kp_b hi  */ }

#define DN_STEP(LS, WS, RB, WB, DO_LOAD, DO_WRITE) {       \
    if (DO_LOAD) DN_LOADSET(LS)                            \
    const char* bb_ = sL + (RB) * 38912;                   \
    s16x8 af0 = *(const s16x8*)(bb_ + aoff0);              \
    s16x8 af1 = *(const s16x8*)(bb_ + aoff1);              \
    s16x8 af2 = *(const s16x8*)(bb_ + aoff2);              \
    s16x8 bf[8];                                           \
    _Pragma("unroll") for (int nf = 0; nf < 8; ++nf) {     \
      const char* p_ = bb_ + boffs[nf];                    \
      union { uint32_t u[4]; s16x8 v; } w_;                \
      w_.u[0] = *(const uint32_t*)p_;                      \
      w_.u[1] = *(const uint32_t*)(p_ + 2048);             \
      w_.u[2] = *(const uint32_t*)(p_ + 4096);             \
      w_.u[3] = *(const uint32_t*)(p_ + 6144);             \
      bf[nf] = w_.v; }                                     \
    WAIT_LGKM0();                                          \
    barrier_raw();                                         \
    if (DO_WRITE) { DN_WRITESET(WS, WB) WAIT_LGKM0(); }    \
    barrier_raw();                                         \
    _Pragma("unroll") for (int nf = 0; nf < 8; ++nf) {     \
      acc[0][nf] = __builtin_amdgcn_mfma_f32_16x16x32_bf16(af0, bf[nf], acc[0][nf], 0, 0, 0); \
      acc[1][nf] = __builtin_amdgcn_mfma_f32_16x16x32_bf16(af1, bf[nf], acc[1][nf], 0, 0, 0); \
      acc[2][nf] = __builtin_amdgcn_mfma_f32_16x16x32_bf16(af2, bf[nf], acc[2][nf], 0, 0, 0); } }

__global__ __launch_bounds__(512, 1) void down_kernel(
    const __hip_bfloat16* __restrict__ Hh, const float* __restrict__ WD,
    const int* __restrict__ cnt, const int* __restrict__ offs,
    const int* __restrict__ tokl, float* __restrict__ Out,
    const int* __restrict__ qm, const int* __restrict__ rgl) {
  __shared__ __align__(16) char sL[2 * 38912];   // per buf: A 6144 + B 32768
  const int tid = threadIdx.x, lane = tid & 63, wid = tid >> 6;
  const int m = lane >> 4, c = lane & 15;
  const int wr = wid >> 2, wc = wid & 3;
  const bool doA = (tid < 192);
  const int arow = tid >> 1, ahalf = tid & 1;
  const int asw = arow & 3;
  const int adst0 = arow * 64 + (((ahalf * 2 + 0) ^ asw) << 4);
  const int adst1 = arow * 64 + (((ahalf * 2 + 1) ^ asw) << 4);
  // B producer dest: kp_a = wid*2, col block lane*4 (u32 units), XOR swizzle
  const int bsw = ((wid >> 1) & 1) << 4;
  const int bdst = 6144 + (wid * 2) * 2048 + (((lane * 4) ^ bsw)) * 4;
  const int aswr = (m ^ (c & 3)) << 4;
  const int aoff0 = (wr * 48 + 0 * 16 + c) * 64 + aswr;
  const int aoff1 = (wr * 48 + 1 * 16 + c) * 64 + aswr;
  const int aoff2 = (wr * 48 + 2 * 16 + c) * 64 + aswr;
  int boffs[8];
#pragma unroll
  for (int nf = 0; nf < 8; ++nf) {
    const int col = wc * 128 + nf * 16 + c;
    boffs[nf] = 6144 + (m * 4) * 2048 + (col ^ ((m & 1) << 4)) * 4;
  }
  const int itot = qm[2] * 4;

  for (int it = blockIdx.x; it < itot; it += 256) {
    const int rg = rgl[it >> 2];
    const int e = rg >> 4, ti = rg & 15, hc = it & 3;
    const int ne = cnt[e];
    const int nrows = min(96, ne - ti * 96);
    const int hb = hc * 512;
    const int cbase = offs[e] + ti * 96;
    const int tbase = e * T_TOK + ti * 96;

    const short* pap = (const short*)Hh
        + (size_t)(cbase + min(arow, nrows - 1)) * IDIM + ahalf * 16;
    const float* pbp = WD + (size_t)e * IDIM * HDIM
        + (size_t)(wid * 4) * HDIM + hb + lane * 4;

    f32x4 acc[3][8];
#pragma unroll
    for (int i = 0; i < 3; ++i)
#pragma unroll
      for (int nf = 0; nf < 8; ++nf)
#pragma unroll
        for (int r = 0; r < 4; ++r) acc[i][nf][r] = 0.f;

    int4  xa0_E{}, xa1_E{}, xa0_O{}, xa1_O{};
    f32x4 v0_E{}, v1_E{}, v2_E{}, v3_E{}, v4_E{}, v5_E{}, v6_E{}, v7_E{};
    f32x4 v0_O{}, v1_O{}, v2_O{}, v3_O{}, v4_O{}, v5_O{}, v6_O{}, v7_O{};

    DN_LOADSET(E)              // tile 0
    DN_LOADSET(O)              // tile 1
    DN_WRITESET(E, 0)
    WAIT_LGKM0();
    barrier_raw();
    for (int p = 0; p < 11; ++p) {      // t = 0..21
      DN_STEP(E, O, 0, 1, true, true)
      DN_STEP(O, E, 1, 0, true, true)
    }
    DN_STEP(E, O, 0, 1, false, true)    // t = 22
    DN_STEP(O, E, 1, 0, false, false)   // t = 23

    // epilogue: fp32 atomic scatter into Out
#pragma unroll
    for (int mi = 0; mi < 3; ++mi) {
      const int rb = wr * 48 + mi * 16 + m * 4;
#pragma unroll
      for (int r = 0; r < 4; ++r) {
        const int row = rb + r;
        if (row < nrows) {
          const int tok = tokl[tbase + row];
          float* op = Out + (size_t)tok * HDIM + hb + wc * 128 + c;
#pragma unroll
          for (int nf = 0; nf < 8; ++nf)
            atomicAdd(op + nf * 16, acc[mi][nf][r]);
        }
      }
    }
    barrier_raw();
  }
}

extern "C" void kernel_launch(void* const* d_in, const int* in_sizes, int n_in,
                              void* d_out, int out_size, void* d_ws, size_t ws_size,
                              hipStream_t stream) {
  (void)in_sizes; (void)n_in; (void)ws_size;
  const float* X  = (const float*)d_in[0];
  const float* GW = (const float*)d_in[1];
  const float* WG = (const float*)d_in[2];
  const float* WU = (const float*)d_in[3];
  const float* WD = (const float*)d_in[4];
  float* Out = (float*)d_out;
  char* ws = (char*)d_ws;

  __hip_bfloat16* Xb = (__hip_bfloat16*)(ws + XBF_OFF);
  int*   cnt  = (int*)(ws + CNT_OFF);
  int*   offs = (int*)(ws + OFF_OFF);
  int*   qm   = (int*)(ws + QM_OFF);
  int*   rgl  = (int*)(ws + RGL_OFF);
  int*   tokl = (int*)(ws + TOK_OFF);
  float* wtl  = (float*)(ws + WT_OFF);
  __hip_bfloat16* Hh = (__hip_bfloat16*)(ws + HH_OFF);

  hipMemsetAsync(ws + CNT_OFF, 0, 1024, stream);  // cnt + offs + qm
  hipMemsetAsync(d_out, 0, (size_t)out_size * sizeof(float), stream);

  router_kernel<<<T_TOK, 256, 0, stream>>>(X, GW, Xb, cnt, tokl, wtl);
  scan_kernel<<<1, 64, 0, stream>>>(cnt, offs, rgl, qm);
  gateup_kernel<<<768, 256, 0, stream>>>(Xb, WG, WU, cnt, offs, tokl, wtl, Hh, qm, rgl);
  down_kernel<<<256, 512, 0, stream>>>(Hh, WD, cnt, offs, tokl, Out, qm, rgl);
}

// Round 11
// 587.032 us; speedup vs baseline: 1.1497x; 1.1497x over previous
//
#include <hip/hip_runtime.h>
#include <hip/hip_bf16.h>
#include <cstddef>
#include <cstdint>

#define T_TOK 1024
#define HDIM  2048
#define NEXP  64
#define IDIM  768
#define TOPK  8

using f32x4 = __attribute__((ext_vector_type(4))) float;
using s16x8 = __attribute__((ext_vector_type(8))) short;

// ---- workspace layout (bytes) ----
static constexpr size_t XBF_OFF = 0;                                   // bf16 X: 4 MiB
static constexpr size_t CNT_OFF = (size_t)T_TOK * HDIM * 2;            // 64 ints
static constexpr size_t OFF_OFF = CNT_OFF + 256;                       // 65 ints
static constexpr size_t QM_OFF  = CNT_OFF + 768;                       // nrg
static constexpr size_t RGL_OFF = CNT_OFF + 1024;                      // rowgroup list
static constexpr size_t TOK_OFF = CNT_OFF + 4096;                      // 64*1024 ints
static constexpr size_t WT_OFF  = TOK_OFF + (size_t)NEXP * T_TOK * 4;  // 64*1024 floats
static constexpr size_t HH_OFF  = WT_OFF  + (size_t)NEXP * T_TOK * 4;  // 8192*768 bf16

__device__ __forceinline__ short f2bf(float f) {
  union { __hip_bfloat16 b; short s; } u;
  u.b = __float2bfloat16(f);
  return u.s;
}
__device__ __forceinline__ uint32_t pk2(float lo, float hi) {
  return ((uint32_t)(uint16_t)f2bf(hi) << 16) | (uint16_t)f2bf(lo);
}
__device__ __forceinline__ void barrier_raw() {
  asm volatile("" ::: "memory");
  __builtin_amdgcn_s_barrier();
  asm volatile("" ::: "memory");
}
#define WAIT_LGKM0() asm volatile("s_waitcnt lgkmcnt(0)" ::: "memory")

// ---------------- router (+ fused fp32->bf16 convert of X) ----------------
__global__ __launch_bounds__(256) void router_kernel(
    const float* __restrict__ X, const float* __restrict__ GW,
    __hip_bfloat16* __restrict__ Xb,
    int* __restrict__ cnt, int* __restrict__ tokl, float* __restrict__ wtl) {
  __shared__ float xs[HDIM];
  __shared__ float lg[NEXP];
  const int t = blockIdx.x;
  const int tid = threadIdx.x;
  const f32x4* xr = (const f32x4*)(X + (size_t)t * HDIM);
#pragma unroll
  for (int i = 0; i < 2; ++i) {
    f32x4 v = xr[tid + i * 256];
    *(f32x4*)&xs[(tid + i * 256) * 4] = v;
  }
  __syncthreads();
  {
    union { short h[8]; int4 q; } u;
#pragma unroll
    for (int j = 0; j < 8; ++j) u.h[j] = f2bf(xs[tid * 8 + j]);
    *(int4*)((char*)Xb + ((size_t)t * HDIM + tid * 8) * 2) = u.q;
  }
  const int wid = tid >> 6, lane = tid & 63;
  for (int ee = 0; ee < 16; ++ee) {
    const int e = wid * 16 + ee;
    const float* g = GW + (size_t)e * HDIM;
    float acc = 0.f;
    for (int i = lane; i < HDIM; i += 64) acc += xs[i] * g[i];
#pragma unroll
    for (int s = 32; s; s >>= 1) acc += __shfl_xor(acc, s);
    if (lane == 0) lg[e] = acc;
  }
  __syncthreads();
  if (tid < 64) {
    const float v = lg[tid];
    float m = v;
#pragma unroll
    for (int s = 32; s; s >>= 1) m = fmaxf(m, __shfl_xor(m, s));
    const float p = expf(v - m);
    float den = p;
#pragma unroll
    for (int s = 32; s; s >>= 1) den += __shfl_xor(den, s);
    float work = p / den;
    float my_v = 0.f; int my_e = 0;
    float topsum = 0.f;
#pragma unroll
    for (int k = 0; k < TOPK; ++k) {
      float mv = work;
#pragma unroll
      for (int s = 32; s; s >>= 1) mv = fmaxf(mv, __shfl_xor(mv, s));
      unsigned long long ball = __ballot(work == mv);
      const int idx = __ffsll(ball) - 1;   // lowest index on ties (matches lax.top_k)
      topsum += mv;
      if (tid == k) { my_v = mv; my_e = idx; }
      if (tid == idx) work = -1.f;
    }
    if (tid < TOPK) {
      const float w = my_v / topsum;
      const int slot = atomicAdd(&cnt[my_e], 1);
      tokl[my_e * T_TOK + slot] = t;
      wtl[my_e * T_TOK + slot] = w;
    }
  }
}

// ---------------- prefix scan + rowgroup list (BM=192) ----------------
__global__ void scan_kernel(const int* __restrict__ cnt, int* __restrict__ offs,
                            int* __restrict__ rgl, int* __restrict__ qm) {
  if (threadIdx.x == 0) {
    int a = 0, nrg = 0;
    for (int e = 0; e < NEXP; ++e) {
      offs[e] = a;
      const int ne = cnt[e];
      a += ne;
      for (int t = 0; t * 192 < ne; ++t) rgl[nrg++] = (e << 4) | t;
    }
    offs[NEXP] = a;
    qm[2] = nrg;
  }
}

// ======================= unified tile geometry =======================
// 512 thr / 8 waves; tile: A 192rows x 32k bf16, B 32k x 256n (fp32->bf16).
// Wave (wr=wid>>2, wc=wid&3): 96 rows x 64 cols -> acc[6][4] f32x4.
// LDS/buf: A 12288 + B 16x1024 = 28672; double buffer = 57344.
// B staged as whole 1KB rows (f32x4 x 64 lanes); kp rows with kp>>2 XOR.
#define LOADA_(S)                                          \
    xa0_##S = *(const int4*)pap;                           \
    xa1_##S = *(const int4*)(pap + 8);                     \
    pap += 32;
#define LOADB_(S, LD)                                      \
    v0_##S = *(const f32x4*)(pbp);                         \
    v1_##S = *(const f32x4*)(pbp + (LD));                  \
    v2_##S = *(const f32x4*)(pbp + 2 * (LD));              \
    v3_##S = *(const f32x4*)(pbp + 3 * (LD));              \
    pbp += (size_t)32 * (LD);
#define LOADSET(S, LD) { if (doA) { LOADA_(S) } LOADB_(S, LD) }

#define WRITESET(S, BUF) {                                 \
    char* base_ = sL + (BUF) * 28672;                      \
    if (doA) {                                             \
      *(int4*)(base_ + adst0) = xa0_##S;                   \
      *(int4*)(base_ + adst1) = xa1_##S;                   \
    }                                                      \
    union { uint32_t u[4]; int4 q; } w_;                   \
    w_.u[0] = pk2(v0_##S[0], v1_##S[0]);                   \
    w_.u[1] = pk2(v0_##S[1], v1_##S[1]);                   \
    w_.u[2] = pk2(v0_##S[2], v1_##S[2]);                   \
    w_.u[3] = pk2(v0_##S[3], v1_##S[3]);                   \
    *(int4*)(base_ + bdst) = w_.q;                         \
    w_.u[0] = pk2(v2_##S[0], v3_##S[0]);                   \
    w_.u[1] = pk2(v2_##S[1], v3_##S[1]);                   \
    w_.u[2] = pk2(v2_##S[2], v3_##S[2]);                   \
    w_.u[3] = pk2(v2_##S[3], v3_##S[3]);                   \
    *(int4*)(base_ + bdst + 1024) = w_.q; }

#define STEP(S_L, S_W, RB, WB, LD, DO_LOAD, DO_WRITE) {    \
    if (DO_LOAD) LOADSET(S_L, LD)                          \
    const char* bb_ = sL + (RB) * 28672;                   \
    s16x8 af[6];                                           \
    _Pragma("unroll") for (int mi = 0; mi < 6; ++mi)       \
      af[mi] = *(const s16x8*)(bb_ + aoffs[mi]);           \
    s16x8 bf[4];                                           \
    _Pragma("unroll") for (int nf = 0; nf < 4; ++nf) {     \
      const char* p_ = bb_ + boffs[nf];                    \
      union { uint32_t u[4]; s16x8 v; } w_;                \
      w_.u[0] = *(const uint32_t*)p_;                      \
      w_.u[1] = *(const uint32_t*)(p_ + 1024);             \
      w_.u[2] = *(const uint32_t*)(p_ + 2048);             \
      w_.u[3] = *(const uint32_t*)(p_ + 3072);             \
      bf[nf] = w_.v; }                                     \
    WAIT_LGKM0();                                          \
    barrier_raw();                                         \
    if (DO_WRITE) { WRITESET(S_W, WB) WAIT_LGKM0(); }      \
    barrier_raw();                                         \
    _Pragma("unroll") for (int mi = 0; mi < 6; ++mi)       \
    _Pragma("unroll") for (int nf = 0; nf < 4; ++nf)       \
      acc[mi][nf] = __builtin_amdgcn_mfma_f32_16x16x32_bf16(af[mi], bf[nf], acc[mi][nf], 0, 0, 0); }

#define TILE_PRELUDE                                       \
  const int tid = threadIdx.x, lane = tid & 63, wid = tid >> 6; \
  const int m = lane >> 4, c = lane & 15;                  \
  const int wr = wid >> 2, wc = wid & 3;                   \
  const bool doA = (tid < 384);                            \
  const int arow = tid >> 1, ahalf = tid & 1;              \
  const int asw = arow & 3;                                \
  const int adst0 = arow * 64 + (((ahalf * 2 + 0) ^ asw) << 4); \
  const int adst1 = arow * 64 + (((ahalf * 2 + 1) ^ asw) << 4); \
  const int bdst = 12288 + (wid * 2) * 1024                \
      + (((lane * 4) ^ (((wid >> 1) & 1) << 4))) * 4;      \
  int aoffs[6];                                            \
  _Pragma("unroll") for (int mi = 0; mi < 6; ++mi)         \
    aoffs[mi] = (wr * 96 + mi * 16 + c) * 64 + ((m ^ (c & 3)) << 4); \
  int boffs[4];                                            \
  _Pragma("unroll") for (int nf = 0; nf < 4; ++nf)         \
    boffs[nf] = 12288 + (m * 4) * 1024                     \
        + ((wc * 64 + nf * 16 + c) ^ ((m & 1) << 4)) * 4;

// ===================== gateup: BM=192, BN=256, 2-pass =====================
__global__ __launch_bounds__(512, 1) void gateup_kernel(
    const __hip_bfloat16* __restrict__ Xb, const float* __restrict__ WG,
    const float* __restrict__ WU, const int* __restrict__ cnt,
    const int* __restrict__ offs, const int* __restrict__ tokl,
    const float* __restrict__ wtl, __hip_bfloat16* __restrict__ Hh,
    const int* __restrict__ qm, const int* __restrict__ rgl) {
  __shared__ __align__(16) char sL[2 * 28672];
  TILE_PRELUDE
  const int itot = qm[2] * 3;

  for (int it = blockIdx.x; it < itot; it += 256) {
    const int rg = rgl[it / 3];
    const int e = rg >> 4, ti = rg & 15, nc = it % 3;
    const int ne = cnt[e];
    const int nrows = min(192, ne - ti * 192);
    const int nb = nc * 256;
    const int cbase = offs[e] + ti * 192;
    const int tbase = e * T_TOK + ti * 192;

    const short* paBase = (const short*)Xb
        + (size_t)tokl[tbase + min(arow, nrows - 1)] * HDIM + ahalf * 16;
    const float* pbG = WG + (size_t)e * HDIM * IDIM + (size_t)(wid * 4) * IDIM + nb + lane * 4;
    const float* pbU = WU + (size_t)e * HDIM * IDIM + (size_t)(wid * 4) * IDIM + nb + lane * 4;

    f32x4 acc[6][4];
    int4  xa0_E{}, xa1_E{}, xa0_O{}, xa1_O{};
    f32x4 v0_E{}, v1_E{}, v2_E{}, v3_E{};
    f32x4 v0_O{}, v1_O{}, v2_O{}, v3_O{};

    for (int pass = 0; pass < 2; ++pass) {
      const short* pap = paBase;
      const float* pbp = pass ? pbU : pbG;
#pragma unroll
      for (int i = 0; i < 6; ++i)
#pragma unroll
        for (int nf = 0; nf < 4; ++nf)
#pragma unroll
          for (int r = 0; r < 4; ++r) acc[i][nf][r] = 0.f;

      LOADSET(E, IDIM)           // tile 0
      LOADSET(O, IDIM)           // tile 1
      WRITESET(E, 0)
      WAIT_LGKM0();
      barrier_raw();
      for (int p = 0; p < 31; ++p) {           // t = 0..61
        STEP(E, O, 0, 1, IDIM, true, true)
        STEP(O, E, 1, 0, IDIM, true, true)
      }
      STEP(E, O, 0, 1, IDIM, false, true)      // t = 62
      STEP(O, E, 1, 0, IDIM, false, false)     // t = 63

      if (pass == 0) {
        // park raw g in Hh
#pragma unroll
        for (int mi = 0; mi < 6; ++mi) {
          const int rb = wr * 96 + mi * 16 + m * 4;
#pragma unroll
          for (int nf = 0; nf < 4; ++nf) {
            const int colg = nb + wc * 64 + nf * 16 + c;
#pragma unroll
            for (int r = 0; r < 4; ++r) {
              const int row = rb + r;
              if (row < nrows)
                Hh[(size_t)(cbase + row) * IDIM + colg] = __float2bfloat16(acc[mi][nf][r]);
            }
          }
        }
        barrier_raw();
      } else {
        // h = silu(g) * u * wt
#pragma unroll
        for (int mi = 0; mi < 6; ++mi) {
          const int rb = wr * 96 + mi * 16 + m * 4;
          const int rbs = min(rb, (nrows - 1) & ~3);
          const f32x4 wt4 = *(const f32x4*)&wtl[tbase + rbs];
#pragma unroll
          for (int nf = 0; nf < 4; ++nf) {
            const int colg = nb + wc * 64 + nf * 16 + c;
#pragma unroll
            for (int r = 0; r < 4; ++r) {
              const int row = rb + r;
              if (row < nrows) {
                __hip_bfloat16* hp = Hh + (size_t)(cbase + row) * IDIM + colg;
                const float g = __bfloat162float(*hp);
                const float uu = acc[mi][nf][r];
                const float h = (g / (1.f + __expf(-g))) * uu * wt4[r];
                *hp = __float2bfloat16(h);
              }
            }
          }
        }
      }
    }
  }
}

// ===================== down: BM=192, BN=256, 24 steps =====================
__global__ __launch_bounds__(512, 1) void down_kernel(
    const __hip_bfloat16* __restrict__ Hh, const float* __restrict__ WD,
    const int* __restrict__ cnt, const int* __restrict__ offs,
    const int* __restrict__ tokl, float* __restrict__ Out,
    const int* __restrict__ qm, const int* __restrict__ rgl) {
  __shared__ __align__(16) char sL[2 * 28672];
  TILE_PRELUDE
  const int itot = qm[2] * 8;

  for (int it = blockIdx.x; it < itot; it += 512) {
    const int rg = rgl[it >> 3];
    const int e = rg >> 4, ti = rg & 15, hc = it & 7;
    const int ne = cnt[e];
    const int nrows = min(192, ne - ti * 192);
    const int hb = hc * 256;
    const int cbase = offs[e] + ti * 192;
    const int tbase = e * T_TOK + ti * 192;

    const short* pap = (const short*)Hh
        + (size_t)(cbase + min(arow, nrows - 1)) * IDIM + ahalf * 16;
    const float* pbp = WD + (size_t)e * IDIM * HDIM
        + (size_t)(wid * 4) * HDIM + hb + lane * 4;

    f32x4 acc[6][4];
#pragma unroll
    for (int i = 0; i < 6; ++i)
#pragma unroll
      for (int nf = 0; nf < 4; ++nf)
#pragma unroll
        for (int r = 0; r < 4; ++r) acc[i][nf][r] = 0.f;

    int4  xa0_E{}, xa1_E{}, xa0_O{}, xa1_O{};
    f32x4 v0_E{}, v1_E{}, v2_E{}, v3_E{};
    f32x4 v0_O{}, v1_O{}, v2_O{}, v3_O{};

    LOADSET(E, HDIM)             // tile 0
    LOADSET(O, HDIM)             // tile 1
    WRITESET(E, 0)
    WAIT_LGKM0();
    barrier_raw();
    for (int p = 0; p < 11; ++p) {           // t = 0..21
      STEP(E, O, 0, 1, HDIM, true, true)
      STEP(O, E, 1, 0, HDIM, true, true)
    }
    STEP(E, O, 0, 1, HDIM, false, true)      // t = 22
    STEP(O, E, 1, 0, HDIM, false, false)     // t = 23

    // epilogue: fp32 atomic scatter into Out
#pragma unroll
    for (int mi = 0; mi < 6; ++mi) {
      const int rb = wr * 96 + mi * 16 + m * 4;
#pragma unroll
      for (int r = 0; r < 4; ++r) {
        const int row = rb + r;
        if (row < nrows) {
          const int tok = tokl[tbase + row];
          float* op = Out + (size_t)tok * HDIM + hb + wc * 64 + c;
#pragma unroll
          for (int nf = 0; nf < 4; ++nf)
            atomicAdd(op + nf * 16, acc[mi][nf][r]);
        }
      }
    }
    barrier_raw();
  }
}

extern "C" void kernel_launch(void* const* d_in, const int* in_sizes, int n_in,
                              void* d_out, int out_size, void* d_ws, size_t ws_size,
                              hipStream_t stream) {
  (void)in_sizes; (void)n_in; (void)ws_size;
  const float* X  = (const float*)d_in[0];
  const float* GW = (const float*)d_in[1];
  const float* WG = (const float*)d_in[2];
  const float* WU = (const float*)d_in[3];
  const float* WD = (const float*)d_in[4];
  float* Out = (float*)d_out;
  char* ws = (char*)d_ws;

  __hip_bfloat16* Xb = (__hip_bfloat16*)(ws + XBF_OFF);
  int*   cnt  = (int*)(ws + CNT_OFF);
  int*   offs = (int*)(ws + OFF_OFF);
  int*   qm   = (int*)(ws + QM_OFF);
  int*   rgl  = (int*)(ws + RGL_OFF);
  int*   tokl = (int*)(ws + TOK_OFF);
  float* wtl  = (float*)(ws + WT_OFF);
  __hip_bfloat16* Hh = (__hip_bfloat16*)(ws + HH_OFF);

  hipMemsetAsync(ws + CNT_OFF, 0, 1024, stream);  // cnt + offs + qm
  hipMemsetAsync(d_out, 0, (size_t)out_size * sizeof(float), stream);

  router_kernel<<<T_TOK, 256, 0, stream>>>(X, GW, Xb, cnt, tokl, wtl);
  scan_kernel<<<1, 64, 0, stream>>>(cnt, offs, rgl, qm);
  gateup_kernel<<<256, 512, 0, stream>>>(Xb, WG, WU, cnt, offs, tokl, wtl, Hh, qm, rgl);
  down_kernel<<<512, 512, 0, stream>>>(Hh, WD, cnt, offs, tokl, Out, qm, rgl);
}